// Round 11
// baseline (202.608 us; speedup 1.0000x reference)
//
#include <hip/hip_runtime.h>
#include <hip/hip_bf16.h>
#include <hip/hip_cooperative_groups.h>

namespace cg = cooperative_groups;

#define BATCH 8
#define SEQ   4096
#define NST   512     // state dim == GEMM K
#define DM    512     // d_model  == GEMM N
#define NCHUNK 64
#define TCH    64     // SEQ / NCHUNK
#define NSUB   4      // sub-chunks per block (two-level scan)
#define RSUB   16     // rows per sub-chunk
#define LDP    (NST + 8)   // LDS row pitch in shorts (2-way bank alias only)

typedef __attribute__((ext_vector_type(4))) float f32x4;
typedef __attribute__((ext_vector_type(8))) short short8v;   // 8 bf16
typedef __attribute__((ext_vector_type(4))) short short4v;

__device__ __forceinline__ short f2bf(float f) {
  union { float f; unsigned u; } v; v.f = f;
  unsigned r = v.u + 0x7FFFu + ((v.u >> 16) & 1u);   // RNE truncate to bf16
  return (short)(r >> 16);
}

// ============================ MEGA (cooperative) ============================
// Single kernel, u read ONCE:
//   transQ (blocks 0-63) -> two-level local scan (rows in REGISTERS, r10's
//   vectorized scheme, seed 0) -> publish chunk sum S -> grid.sync ->
//   xin from S -> in-register correction -> X bf16 -> GEMM -> PLAIN stores.
// r6-r8's 3x slowdown was NT *scalar* y stores (WRITE 88-94MB, ~100us store
// phase), NOT the coop launch: MFMA-busy time was identical. Plain stores here.
__global__ __launch_bounds__(512) void k_mega(
    const float* __restrict__ u, const float* __restrict__ Lam,
    const float* __restrict__ Bv, const float* __restrict__ log_dt,
    const float* __restrict__ Q, float* __restrict__ S,
    short* __restrict__ Qt, float* __restrict__ y) {
  __shared__ __align__(16) short X[TCH][LDP];      // 66560 B
  __shared__ __align__(16) float Ssub[NSUB][NST];  // 8192 B
  const int tid = threadIdx.x;
  const int b = blockIdx.x & (BATCH - 1);
  const int c = blockIdx.x >> 3;
  const int tq = tid >> 7;                       // sub-chunk 0..3
  const int q  = tid & 127;                      // col group
  const int n0 = q * 4;

  // ---- phase 0: transQ, blocks 0..63 (X LDS used as scratch, then freed)
  if (blockIdx.x < 64) {
    short (*tile)[68] = (short(*)[68])&X[0][0];
    const int bn = (blockIdx.x & 7) * 64;
    const int bd = (blockIdx.x >> 3) * 64;
    const int tc4 = (tid & 15) * 4;
    const int tr = tid >> 4;                     // 0..31
    #pragma unroll
    for (int i = 0; i < 2; ++i) {
      int r = tr + i * 32;                       // n-local
      f32x4 v = *(const f32x4*)(Q + (size_t)(bn + r) * DM + bd + tc4);
      short4v h;
      h[0] = f2bf(v[0]); h[1] = f2bf(v[1]); h[2] = f2bf(v[2]); h[3] = f2bf(v[3]);
      *(short4v*)&tile[r][tc4] = h;
    }
    __syncthreads();
    #pragma unroll
    for (int i = 0; i < 2; ++i) {
      int r = tr + i * 32;                       // d-local
      short4v h;
      #pragma unroll
      for (int j = 0; j < 4; ++j) h[j] = tile[tc4 + j][r];
      *(short4v*)(Qt + (size_t)(bd + r) * NST + bn + tc4) = h;
    }
    __syncthreads();                             // X free again
  }

  // ---- per-thread scan coefficients (4 columns) ----
  const float dtv = expf(log_dt[0]);
  f32x4 lam = *(const f32x4*)(Lam + n0);
  f32x4 bv  = *(const f32x4*)(Bv + n0);
  float a[4], g[4], a16[4];
  #pragma unroll
  for (int i = 0; i < 4; ++i) {
    a[i] = expf(-dtv * expf(lam[i]));
    g[i] = dtv * bv[i];
    float t = a[i]; t *= t; t *= t; t *= t; t *= t;   // a^16
    a16[i] = t;
  }

  // ---- phase 1: local scan from 0 (rows stay in registers) ----
  const float* up = u + ((size_t)b * SEQ + (size_t)(c * TCH + tq * RSUB)) * NST + n0;
  f32x4 v[RSUB];
  #pragma unroll
  for (int j = 0; j < RSUB; ++j) v[j] = *(const f32x4*)(up + (size_t)j * NST);
  {
    f32x4 x = (f32x4){0.f, 0.f, 0.f, 0.f};
    #pragma unroll
    for (int j = 0; j < RSUB; ++j) {
      #pragma unroll
      for (int i = 0; i < 4; ++i) x[i] = fmaf(a[i], x[i], g[i] * v[j][i]);
      v[j] = x;
    }
    *(f32x4*)&Ssub[tq][n0] = x;                  // sub-chunk end state
  }
  __syncthreads();

  // ---- publish chunk-local sum: S[c] = Ssub3 + a16*(Ssub2 + a16*(Ssub1 + a16*Ssub0))
  if (tq == 0) {
    f32x4 s0 = *(const f32x4*)&Ssub[0][n0];
    f32x4 s1 = *(const f32x4*)&Ssub[1][n0];
    f32x4 s2 = *(const f32x4*)&Ssub[2][n0];
    f32x4 s3 = *(const f32x4*)&Ssub[3][n0];
    f32x4 cs;
    #pragma unroll
    for (int i = 0; i < 4; ++i)
      cs[i] = fmaf(a16[i], fmaf(a16[i], fmaf(a16[i], s0[i], s1[i]), s2[i]), s3[i]);
    *(f32x4*)(S + (c * BATCH + b) * NST + n0) = cs;
  }
  __threadfence();
  cg::this_grid().sync();

  // ---- phase 2: chunk-incoming state xin from S[c'<c] ----
  float a64[4];
  #pragma unroll
  for (int i = 0; i < 4; ++i) { float t = a16[i]; t *= t; t *= t; a64[i] = t; }
  f32x4 xin = (f32x4){0.f, 0.f, 0.f, 0.f};
  {
    int cp = 0;
    for (; cp + 8 <= c; cp += 8) {
      f32x4 sb[8];
      #pragma unroll
      for (int j = 0; j < 8; ++j) sb[j] = *(const f32x4*)(S + ((cp + j) * BATCH + b) * NST + n0);
      #pragma unroll
      for (int j = 0; j < 8; ++j)
        #pragma unroll
        for (int i = 0; i < 4; ++i) xin[i] = fmaf(a64[i], xin[i], sb[j][i]);
    }
    for (; cp < c; ++cp) {
      f32x4 sv = *(const f32x4*)(S + (cp * BATCH + b) * NST + n0);
      #pragma unroll
      for (int i = 0; i < 4; ++i) xin[i] = fmaf(a64[i], xin[i], sv[i]);
    }
  }

  // ---- sub-chunk incoming I(tq) = evolve(xin through subs < tq) ----
  f32x4 I = xin;
  for (int s = 0; s < tq; ++s) {                 // wave-uniform trip count
    f32x4 sv = *(const f32x4*)&Ssub[s][n0];
    #pragma unroll
    for (int i = 0; i < 4; ++i) I[i] = fmaf(a16[i], I[i], sv[i]);
  }

  // ---- phase 3: in-register correction x[j] += a^{j+1}*I, write X bf16 ----
  {
    f32x4 ap;
    #pragma unroll
    for (int i = 0; i < 4; ++i) ap[i] = a[i];
    #pragma unroll
    for (int j = 0; j < RSUB; ++j) {
      short4v h;
      #pragma unroll
      for (int i = 0; i < 4; ++i) {
        v[j][i] = fmaf(ap[i], I[i], v[j][i]);
        ap[i] *= a[i];
      }
      h[0] = f2bf(v[j][0]); h[1] = f2bf(v[j][1]);
      h[2] = f2bf(v[j][2]); h[3] = f2bf(v[j][3]);
      *(short4v*)&X[tq * RSUB + j][n0] = h;
    }
  }
  __syncthreads();

  // ---- phase 4: GEMM 64x512x512; wave wc owns 64 cols x all 64 rows ----
  const int lane = tid & 63;
  const int wc   = tid >> 6;                     // 0..7
  const int l15  = lane & 15;
  const int lhi  = lane >> 4;
  const int ka   = lhi * 8;                      // k offset within BK=32
  const short* qbase = Qt + (size_t)(wc * 64 + l15) * NST + ka;
  float* yb = y + ((size_t)b * SEQ + (size_t)c * TCH) * DM;

  f32x4 acc[4][4];
  #pragma unroll
  for (int mi = 0; mi < 4; ++mi)
    #pragma unroll
    for (int nf = 0; nf < 4; ++nf) acc[mi][nf] = (f32x4){0.f, 0.f, 0.f, 0.f};

  #pragma unroll 4
  for (int kk = 0; kk < 16; ++kk) {
    const int k0 = kk * 32;
    short8v afrag[4];
    #pragma unroll
    for (int mi = 0; mi < 4; ++mi)
      afrag[mi] = *(const short8v*)&X[mi * 16 + l15][k0 + ka];
    short8v bfrag[4];
    #pragma unroll
    for (int nf = 0; nf < 4; ++nf)
      bfrag[nf] = *(const short8v*)(qbase + (size_t)nf * 16 * NST + k0);
    #pragma unroll
    for (int mi = 0; mi < 4; ++mi)
      #pragma unroll
      for (int nf = 0; nf < 4; ++nf)
        acc[mi][nf] = __builtin_amdgcn_mfma_f32_16x16x32_bf16(afrag[mi], bfrag[nf], acc[mi][nf], 0, 0, 0);
  }

  // ---- y stores: PLAIN scalar stores (L2 write-coalescing; NT scalar = poison)
  #pragma unroll
  for (int mi = 0; mi < 4; ++mi)
    #pragma unroll
    for (int nf = 0; nf < 4; ++nf) {
      const int rr = mi * 16 + lhi * 4;
      const int cc = wc * 64 + nf * 16 + l15;
      #pragma unroll
      for (int i = 0; i < 4; ++i)
        yb[(size_t)(rr + i) * DM + cc] = acc[mi][nf][i];
    }
}

// ============================ FALLBACK (round-10 path) ============================
__global__ void k_scan_sums(const float* __restrict__ u, const float* __restrict__ Lam,
                            const float* __restrict__ Bv, const float* __restrict__ log_dt,
                            float* __restrict__ S) {
  int gid = blockIdx.x * 128 + threadIdx.x;
  int n0 = (gid & 127) * 4;
  int bc = gid >> 7;
  int b  = bc & (BATCH - 1);
  int c  = bc >> 3;
  float dt = expf(log_dt[0]);
  f32x4 lam = *(const f32x4*)(Lam + n0);
  f32x4 bv  = *(const f32x4*)(Bv + n0);
  float a[4], g[4];
  #pragma unroll
  for (int i = 0; i < 4; ++i) { a[i] = expf(-dt * expf(lam[i])); g[i] = dt * bv[i]; }
  const float* up = u + ((size_t)b * SEQ + (size_t)c * TCH) * NST + n0;
  f32x4 s = (f32x4){0.f, 0.f, 0.f, 0.f};
  #pragma unroll 8
  for (int t = 0; t < TCH; ++t) {
    f32x4 v = *(const f32x4*)(up + (size_t)t * NST);
    #pragma unroll
    for (int i = 0; i < 4; ++i) s[i] = fmaf(a[i], s[i], g[i] * v[i]);
  }
  *(f32x4*)(S + (c * BATCH + b) * NST + n0) = s;
}

__global__ void k_propagate(const float* __restrict__ Lam, const float* __restrict__ log_dt,
                            const float* __restrict__ S, float* __restrict__ Xc) {
  int gid = blockIdx.x * 256 + threadIdx.x;
  int n = gid & (NST - 1);
  int b = gid >> 9;
  float dt = expf(log_dt[0]);
  float a  = expf(-dt * expf(Lam[n]));
  float aT = a;
  #pragma unroll
  for (int i = 0; i < 6; ++i) aT *= aT;          // a^64
  float x = 0.f;
  for (int c = 0; c < NCHUNK; ++c) {
    Xc[(c * BATCH + b) * NST + n] = x;
    x = fmaf(aT, x, S[(c * BATCH + b) * NST + n]);
  }
}

__global__ void k_transQ(const float* __restrict__ Q, short* __restrict__ Qt) {
  __shared__ short tile[64][68];
  int bn = (blockIdx.x & 7) * 64;
  int bd = (blockIdx.x >> 3) * 64;
  int tc = threadIdx.x & 15;
  int tr = threadIdx.x >> 4;
  #pragma unroll
  for (int i = 0; i < 4; ++i) {
    int r = tr + i * 16;
    f32x4 v = *(const f32x4*)(Q + (size_t)(bn + r) * DM + bd + tc * 4);
    short4v h;
    h[0] = f2bf(v[0]); h[1] = f2bf(v[1]); h[2] = f2bf(v[2]); h[3] = f2bf(v[3]);
    *(short4v*)&tile[r][tc * 4] = h;
  }
  __syncthreads();
  #pragma unroll
  for (int i = 0; i < 4; ++i) {
    int r = tr + i * 16;
    short4v h;
    #pragma unroll
    for (int j = 0; j < 4; ++j) h[j] = tile[tc * 4 + j][r];
    *(short4v*)(Qt + (size_t)(bd + r) * NST + bn + tc * 4) = h;
  }
}

__global__ __launch_bounds__(512) void k_fused(
    const float* __restrict__ u, const float* __restrict__ Lam,
    const float* __restrict__ Bv, const float* __restrict__ log_dt,
    const float* __restrict__ Xc, const short* __restrict__ Qt,
    float* __restrict__ y) {
  __shared__ __align__(16) short X[TCH][LDP];
  __shared__ __align__(16) float Ssub[NSUB][NST];
  const int tid = threadIdx.x;
  const int b = blockIdx.x & (BATCH - 1);
  const int c = blockIdx.x >> 3;
  const int tq = tid >> 7;
  const int q  = tid & 127;
  const int n0 = q * 4;
  {
    const float dt = expf(log_dt[0]);
    f32x4 lam = *(const f32x4*)(Lam + n0);
    f32x4 bv  = *(const f32x4*)(Bv + n0);
    float a[4], g[4], a16[4];
    #pragma unroll
    for (int i = 0; i < 4; ++i) {
      a[i] = expf(-dt * expf(lam[i]));
      g[i] = dt * bv[i];
      float t = a[i]; t *= t; t *= t; t *= t; t *= t;
      a16[i] = t;
    }
    f32x4 seed = (f32x4){0.f, 0.f, 0.f, 0.f};
    if (tq == 0) seed = *(const f32x4*)(Xc + (c * BATCH + b) * NST + n0);
    const float* up = u + ((size_t)b * SEQ + (size_t)(c * TCH + tq * RSUB)) * NST + n0;
    f32x4 v[RSUB];
    #pragma unroll
    for (int j = 0; j < RSUB; ++j) v[j] = *(const f32x4*)(up + (size_t)j * NST);
    f32x4 x = seed;
    #pragma unroll
    for (int j = 0; j < RSUB; ++j) {
      #pragma unroll
      for (int i = 0; i < 4; ++i) x[i] = fmaf(a[i], x[i], g[i] * v[j][i]);
      v[j] = x;
    }
    *(f32x4*)&Ssub[tq][n0] = x;
    __syncthreads();
    if (tq > 0) {
      f32x4 I = *(const f32x4*)&Ssub[0][n0];
      for (int s = 1; s < tq; ++s) {
        f32x4 sv = *(const f32x4*)&Ssub[s][n0];
        #pragma unroll
        for (int i = 0; i < 4; ++i) I[i] = fmaf(a16[i], I[i], sv[i]);
      }
      f32x4 ap;
      #pragma unroll
      for (int i = 0; i < 4; ++i) ap[i] = a[i];
      #pragma unroll
      for (int j = 0; j < RSUB; ++j)
        #pragma unroll
        for (int i = 0; i < 4; ++i) {
          v[j][i] = fmaf(ap[i], I[i], v[j][i]);
          ap[i] *= a[i];
        }
    }
    #pragma unroll
    for (int j = 0; j < RSUB; ++j) {
      short4v h;
      h[0] = f2bf(v[j][0]); h[1] = f2bf(v[j][1]);
      h[2] = f2bf(v[j][2]); h[3] = f2bf(v[j][3]);
      *(short4v*)&X[tq * RSUB + j][n0] = h;
    }
  }
  __syncthreads();
  const int lane = tid & 63;
  const int wc   = tid >> 6;
  const int l15  = lane & 15;
  const int lhi  = lane >> 4;
  const int ka   = lhi * 8;
  const short* qbase = Qt + (size_t)(wc * 64 + l15) * NST + ka;
  float* yb = y + ((size_t)b * SEQ + (size_t)c * TCH) * DM;
  f32x4 acc[4][4];
  #pragma unroll
  for (int mi = 0; mi < 4; ++mi)
    #pragma unroll
    for (int nf = 0; nf < 4; ++nf) acc[mi][nf] = (f32x4){0.f, 0.f, 0.f, 0.f};
  #pragma unroll 4
  for (int kk = 0; kk < 16; ++kk) {
    const int k0 = kk * 32;
    short8v afrag[4];
    #pragma unroll
    for (int mi = 0; mi < 4; ++mi)
      afrag[mi] = *(const short8v*)&X[mi * 16 + l15][k0 + ka];
    short8v bfrag[4];
    #pragma unroll
    for (int nf = 0; nf < 4; ++nf)
      bfrag[nf] = *(const short8v*)(qbase + (size_t)nf * 16 * NST + k0);
    #pragma unroll
    for (int mi = 0; mi < 4; ++mi)
      #pragma unroll
      for (int nf = 0; nf < 4; ++nf)
        acc[mi][nf] = __builtin_amdgcn_mfma_f32_16x16x32_bf16(afrag[mi], bfrag[nf], acc[mi][nf], 0, 0, 0);
  }
  #pragma unroll
  for (int mi = 0; mi < 4; ++mi)
    #pragma unroll
    for (int nf = 0; nf < 4; ++nf) {
      const int rr = mi * 16 + lhi * 4;
      const int cc = wc * 64 + nf * 16 + l15;
      #pragma unroll
      for (int i = 0; i < 4; ++i)
        yb[(size_t)(rr + i) * DM + cc] = acc[mi][nf][i];
    }
}

extern "C" void kernel_launch(void* const* d_in, const int* in_sizes, int n_in,
                              void* d_out, int out_size, void* d_ws, size_t ws_size,
                              hipStream_t stream) {
  const float* u      = (const float*)d_in[0];
  const float* Lam    = (const float*)d_in[1];
  const float* Bv     = (const float*)d_in[2];
  const float* Q      = (const float*)d_in[3];
  const float* log_dt = (const float*)d_in[4];
  float* out = (float*)d_out;

  float* S  = (float*)d_ws;                                  // 1 MB
  float* Xc = S + NCHUNK * BATCH * NST;                      // 1 MB (fallback only)
  short* Qt = (short*)(Xc + NCHUNK * BATCH * NST);           // 512 KB bf16

  void* args[] = {(void*)&u, (void*)&Lam, (void*)&Bv, (void*)&log_dt,
                  (void*)&Q, (void*)&S, (void*)&Qt, (void*)&out};
  hipError_t e = hipLaunchCooperativeKernel((const void*)k_mega,
                                            dim3(NCHUNK * BATCH), dim3(512),
                                            args, 0, stream);
  if (e != hipSuccess) {
    // fallback: proven round-10 four-kernel path (identical output)
    hipLaunchKernelGGL(k_transQ, dim3(64), dim3(256), 0, stream, Q, Qt);
    hipLaunchKernelGGL(k_scan_sums, dim3(NCHUNK * BATCH), dim3(128), 0, stream,
                       u, Lam, Bv, log_dt, S);
    hipLaunchKernelGGL(k_propagate, dim3(BATCH * NST / 256), dim3(256), 0, stream,
                       Lam, log_dt, S, Xc);
    hipLaunchKernelGGL(k_fused, dim3(NCHUNK * BATCH), dim3(512), 0, stream,
                       u, Lam, Bv, log_dt, Xc, Qt, out);
  }
}

// Round 12
// 72.275 us; speedup vs baseline: 2.8033x; 2.8033x over previous
//
#include <hip/hip_runtime.h>
#include <hip/hip_bf16.h>

#define BATCH 8
#define SEQ   4096
#define NST   512     // state dim == GEMM K
#define DM    512     // d_model  == GEMM N
#define NCHUNK 64
#define TCH    64     // SEQ / NCHUNK
#define NSUB   4      // sub-chunks per block (r10 fallback)
#define RSUB   16
#define LDP    (NST + 8)   // LDS row pitch in shorts (2-way bank alias only)

typedef __attribute__((ext_vector_type(4))) float f32x4;
typedef __attribute__((ext_vector_type(8))) short short8v;   // 8 bf16
typedef __attribute__((ext_vector_type(4))) short short4v;

__device__ __forceinline__ short f2bf(float f) {
  union { float f; unsigned u; } v; v.f = f;
  unsigned r = v.u + 0x7FFFu + ((v.u >> 16) & 1u);   // RNE truncate to bf16
  return (short)(r >> 16);
}
__device__ __forceinline__ float bf2f(short s) {
  union { unsigned u; float f; } v; v.u = ((unsigned)(unsigned short)s) << 16;
  return v.f;
}

// ============ K1: local scan from 0; write bf16 XL (32MB) + chunk sum S ============
// Block = (c,b), 128 threads; thread owns 4 cols x 64 rows. u read ONCE here.
__global__ __launch_bounds__(128) void k_scan_store(
    const float* __restrict__ u, const float* __restrict__ Lam,
    const float* __restrict__ Bv, const float* __restrict__ log_dt,
    float* __restrict__ S, short* __restrict__ XL) {
  const int q  = threadIdx.x;                    // col group
  const int n0 = q * 4;
  const int b  = blockIdx.x & (BATCH - 1);
  const int c  = blockIdx.x >> 3;
  const float dt = expf(log_dt[0]);
  f32x4 lam = *(const f32x4*)(Lam + n0);
  f32x4 bv  = *(const f32x4*)(Bv + n0);
  float a[4], g[4];
  #pragma unroll
  for (int i = 0; i < 4; ++i) { a[i] = expf(-dt * expf(lam[i])); g[i] = dt * bv[i]; }
  const float* up = u  + ((size_t)b * SEQ + (size_t)c * TCH) * NST + n0;
  short*      xp = XL + ((size_t)b * SEQ + (size_t)c * TCH) * NST + n0;
  f32x4 x = (f32x4){0.f, 0.f, 0.f, 0.f};
  for (int t0 = 0; t0 < TCH; t0 += 8) {
    f32x4 w[8];
    #pragma unroll
    for (int j = 0; j < 8; ++j) w[j] = *(const f32x4*)(up + (size_t)(t0 + j) * NST);
    #pragma unroll
    for (int j = 0; j < 8; ++j) {
      #pragma unroll
      for (int i = 0; i < 4; ++i) x[i] = fmaf(a[i], x[i], g[i] * w[j][i]);
      short4v h;
      h[0] = f2bf(x[0]); h[1] = f2bf(x[1]); h[2] = f2bf(x[2]); h[3] = f2bf(x[3]);
      *(short4v*)(xp + (size_t)(t0 + j) * NST) = h;
    }
  }
  *(f32x4*)(S + (c * BATCH + b) * NST + n0) = x;  // full-precision chunk sum
}

// ============ K2: chunk-state propagation (unchanged, proven) ============
__global__ void k_propagate(const float* __restrict__ Lam, const float* __restrict__ log_dt,
                            const float* __restrict__ S, float* __restrict__ Xc) {
  int gid = blockIdx.x * 256 + threadIdx.x;      // [0, BATCH*NST)
  int n = gid & (NST - 1);
  int b = gid >> 9;
  float dt = expf(log_dt[0]);
  float a  = expf(-dt * expf(Lam[n]));
  float aT = a;
  #pragma unroll
  for (int i = 0; i < 6; ++i) aT *= aT;          // a^64 = a^TCH
  float x = 0.f;
  for (int c = 0; c < NCHUNK; ++c) {
    Xc[(c * BATCH + b) * NST + n] = x;
    x = fmaf(aT, x, S[(c * BATCH + b) * NST + n]);
  }
}

// ============ K3: Qt[d][n] = bf16(Q[n][d]) (unchanged, proven) ============
__global__ void k_transQ(const float* __restrict__ Q, short* __restrict__ Qt) {
  __shared__ short tile[64][68];
  int bn = (blockIdx.x & 7) * 64;
  int bd = (blockIdx.x >> 3) * 64;
  int tc = threadIdx.x & 15;
  int tr = threadIdx.x >> 4;
  #pragma unroll
  for (int i = 0; i < 4; ++i) {
    int r = tr + i * 16;
    f32x4 v = *(const f32x4*)(Q + (size_t)(bn + r) * DM + bd + tc * 4);
    short4v h;
    h[0] = f2bf(v[0]); h[1] = f2bf(v[1]); h[2] = f2bf(v[2]); h[3] = f2bf(v[3]);
    *(short4v*)&tile[r][tc * 4] = h;
  }
  __syncthreads();
  #pragma unroll
  for (int i = 0; i < 4; ++i) {
    int r = tr + i * 16;
    short4v h;
    #pragma unroll
    for (int j = 0; j < 4; ++j) h[j] = tile[tc * 4 + j][r];
    *(short4v*)(Qt + (size_t)(bd + r) * NST + bn + tc * 4) = h;
  }
}

// ============ K4: XL(L3) -> correction -> LDS X -> GEMM -> y (r10 GEMM verbatim) ============
// Thread (tq,q) owns rows [tq*16..+16) x cols [4q..+4).
// x[t] = bf(xl[t]) + a^{t+1}*xin ; a^{t+1} = a16^tq * a^{j+1}.
__global__ __launch_bounds__(512) void k_fusedB(
    const float* __restrict__ Lam, const float* __restrict__ Bv,
    const float* __restrict__ log_dt, const float* __restrict__ Xc,
    const short* __restrict__ XL, const short* __restrict__ Qt,
    float* __restrict__ y) {
  __shared__ __align__(16) short X[TCH][LDP];    // 66560 B -> 2 blocks/CU
  const int tid = threadIdx.x;
  const int b = blockIdx.x & (BATCH - 1);
  const int c = blockIdx.x >> 3;
  const int tq = tid >> 7;                       // sub-chunk 0..3
  const int q  = tid & 127;
  const int n0 = q * 4;

  // ---- phase A: load local-scan rows, apply prefix correction, write LDS ----
  {
    const float dt = expf(log_dt[0]);
    f32x4 lam = *(const f32x4*)(Lam + n0);
    float a[4], ap[4];
    #pragma unroll
    for (int i = 0; i < 4; ++i) a[i] = expf(-dt * expf(lam[i]));
    // ap = a^{tq*16+1}
    #pragma unroll
    for (int i = 0; i < 4; ++i) {
      float t16 = a[i]; t16 *= t16; t16 *= t16; t16 *= t16; t16 *= t16;  // a^16
      float p = a[i];
      float base = t16;
      int e = tq;                                 // a^{16*tq} via 2-bit exponent
      if (e & 1) p *= base;
      base *= base;                               // a^32
      if (e & 2) p *= base;
      ap[i] = p;
    }
    f32x4 xin = *(const f32x4*)(Xc + (c * BATCH + b) * NST + n0);
    const short* xp = XL + ((size_t)b * SEQ + (size_t)(c * TCH + tq * RSUB)) * NST + n0;
    short4v hv[RSUB];
    #pragma unroll
    for (int j = 0; j < RSUB; ++j) hv[j] = *(const short4v*)(xp + (size_t)j * NST);
    #pragma unroll
    for (int j = 0; j < RSUB; ++j) {
      short4v h;
      #pragma unroll
      for (int i = 0; i < 4; ++i) {
        float xv = fmaf(ap[i], xin[i], bf2f(hv[j][i]));
        ap[i] *= a[i];
        h[i] = f2bf(xv);
      }
      *(short4v*)&X[tq * RSUB + j][n0] = h;
    }
  }
  __syncthreads();

  // ---- phase B: GEMM 64x512x512; wave wc owns 64 cols x all 64 rows ----
  const int lane = tid & 63;
  const int wc   = tid >> 6;
  const int l15  = lane & 15;
  const int lhi  = lane >> 4;
  const int ka   = lhi * 8;
  const short* qbase = Qt + (size_t)(wc * 64 + l15) * NST + ka;
  float* yb = y + ((size_t)b * SEQ + (size_t)c * TCH) * DM;

  f32x4 acc[4][4];
  #pragma unroll
  for (int mi = 0; mi < 4; ++mi)
    #pragma unroll
    for (int nf = 0; nf < 4; ++nf) acc[mi][nf] = (f32x4){0.f, 0.f, 0.f, 0.f};

  #pragma unroll 4
  for (int kk = 0; kk < 16; ++kk) {
    const int k0 = kk * 32;
    short8v afrag[4];
    #pragma unroll
    for (int mi = 0; mi < 4; ++mi)
      afrag[mi] = *(const short8v*)&X[mi * 16 + l15][k0 + ka];
    short8v bfrag[4];
    #pragma unroll
    for (int nf = 0; nf < 4; ++nf)
      bfrag[nf] = *(const short8v*)(qbase + (size_t)nf * 16 * NST + k0);
    #pragma unroll
    for (int mi = 0; mi < 4; ++mi)
      #pragma unroll
      for (int nf = 0; nf < 4; ++nf)
        acc[mi][nf] = __builtin_amdgcn_mfma_f32_16x16x32_bf16(afrag[mi], bfrag[nf], acc[mi][nf], 0, 0, 0);
  }

  #pragma unroll
  for (int mi = 0; mi < 4; ++mi)
    #pragma unroll
    for (int nf = 0; nf < 4; ++nf) {
      const int rr = mi * 16 + lhi * 4;
      const int cc = wc * 64 + nf * 16 + l15;
      #pragma unroll
      for (int i = 0; i < 4; ++i)
        yb[(size_t)(rr + i) * DM + cc] = acc[mi][nf][i];
    }
}

// ============================ FALLBACK (round-10 path) ============================
__global__ void k_scan_sums(const float* __restrict__ u, const float* __restrict__ Lam,
                            const float* __restrict__ Bv, const float* __restrict__ log_dt,
                            float* __restrict__ S) {
  int gid = blockIdx.x * 128 + threadIdx.x;
  int n0 = (gid & 127) * 4;
  int bc = gid >> 7;
  int b  = bc & (BATCH - 1);
  int c  = bc >> 3;
  float dt = expf(log_dt[0]);
  f32x4 lam = *(const f32x4*)(Lam + n0);
  f32x4 bv  = *(const f32x4*)(Bv + n0);
  float a[4], g[4];
  #pragma unroll
  for (int i = 0; i < 4; ++i) { a[i] = expf(-dt * expf(lam[i])); g[i] = dt * bv[i]; }
  const float* up = u + ((size_t)b * SEQ + (size_t)c * TCH) * NST + n0;
  f32x4 s = (f32x4){0.f, 0.f, 0.f, 0.f};
  #pragma unroll 8
  for (int t = 0; t < TCH; ++t) {
    f32x4 v = *(const f32x4*)(up + (size_t)t * NST);
    #pragma unroll
    for (int i = 0; i < 4; ++i) s[i] = fmaf(a[i], s[i], g[i] * v[i]);
  }
  *(f32x4*)(S + (c * BATCH + b) * NST + n0) = s;
}

__global__ __launch_bounds__(512) void k_fused(
    const float* __restrict__ u, const float* __restrict__ Lam,
    const float* __restrict__ Bv, const float* __restrict__ log_dt,
    const float* __restrict__ Xc, const short* __restrict__ Qt,
    float* __restrict__ y) {
  __shared__ __align__(16) short X[TCH][LDP];
  __shared__ __align__(16) float Ssub[NSUB][NST];
  const int tid = threadIdx.x;
  const int b = blockIdx.x & (BATCH - 1);
  const int c = blockIdx.x >> 3;
  const int tq = tid >> 7;
  const int q  = tid & 127;
  const int n0 = q * 4;
  {
    const float dt = expf(log_dt[0]);
    f32x4 lam = *(const f32x4*)(Lam + n0);
    f32x4 bv  = *(const f32x4*)(Bv + n0);
    float a[4], g[4], a16[4];
    #pragma unroll
    for (int i = 0; i < 4; ++i) {
      a[i] = expf(-dt * expf(lam[i]));
      g[i] = dt * bv[i];
      float t = a[i]; t *= t; t *= t; t *= t; t *= t;
      a16[i] = t;
    }
    f32x4 seed = (f32x4){0.f, 0.f, 0.f, 0.f};
    if (tq == 0) seed = *(const f32x4*)(Xc + (c * BATCH + b) * NST + n0);
    const float* up = u + ((size_t)b * SEQ + (size_t)(c * TCH + tq * RSUB)) * NST + n0;
    f32x4 v[RSUB];
    #pragma unroll
    for (int j = 0; j < RSUB; ++j) v[j] = *(const f32x4*)(up + (size_t)j * NST);
    f32x4 x = seed;
    #pragma unroll
    for (int j = 0; j < RSUB; ++j) {
      #pragma unroll
      for (int i = 0; i < 4; ++i) x[i] = fmaf(a[i], x[i], g[i] * v[j][i]);
      v[j] = x;
    }
    *(f32x4*)&Ssub[tq][n0] = x;
    __syncthreads();
    if (tq > 0) {
      f32x4 I = *(const f32x4*)&Ssub[0][n0];
      for (int s = 1; s < tq; ++s) {
        f32x4 sv = *(const f32x4*)&Ssub[s][n0];
        #pragma unroll
        for (int i = 0; i < 4; ++i) I[i] = fmaf(a16[i], I[i], sv[i]);
      }
      f32x4 ap;
      #pragma unroll
      for (int i = 0; i < 4; ++i) ap[i] = a[i];
      #pragma unroll
      for (int j = 0; j < RSUB; ++j)
        #pragma unroll
        for (int i = 0; i < 4; ++i) {
          v[j][i] = fmaf(ap[i], I[i], v[j][i]);
          ap[i] *= a[i];
        }
    }
    #pragma unroll
    for (int j = 0; j < RSUB; ++j) {
      short4v h;
      h[0] = f2bf(v[j][0]); h[1] = f2bf(v[j][1]);
      h[2] = f2bf(v[j][2]); h[3] = f2bf(v[j][3]);
      *(short4v*)&X[tq * RSUB + j][n0] = h;
    }
  }
  __syncthreads();
  const int lane = tid & 63;
  const int wc   = tid >> 6;
  const int l15  = lane & 15;
  const int lhi  = lane >> 4;
  const int ka   = lhi * 8;
  const short* qbase = Qt + (size_t)(wc * 64 + l15) * NST + ka;
  float* yb = y + ((size_t)b * SEQ + (size_t)c * TCH) * DM;
  f32x4 acc[4][4];
  #pragma unroll
  for (int mi = 0; mi < 4; ++mi)
    #pragma unroll
    for (int nf = 0; nf < 4; ++nf) acc[mi][nf] = (f32x4){0.f, 0.f, 0.f, 0.f};
  #pragma unroll 4
  for (int kk = 0; kk < 16; ++kk) {
    const int k0 = kk * 32;
    short8v afrag[4];
    #pragma unroll
    for (int mi = 0; mi < 4; ++mi)
      afrag[mi] = *(const short8v*)&X[mi * 16 + l15][k0 + ka];
    short8v bfrag[4];
    #pragma unroll
    for (int nf = 0; nf < 4; ++nf)
      bfrag[nf] = *(const short8v*)(qbase + (size_t)nf * 16 * NST + k0);
    #pragma unroll
    for (int mi = 0; mi < 4; ++mi)
      #pragma unroll
      for (int nf = 0; nf < 4; ++nf)
        acc[mi][nf] = __builtin_amdgcn_mfma_f32_16x16x32_bf16(afrag[mi], bfrag[nf], acc[mi][nf], 0, 0, 0);
  }
  #pragma unroll
  for (int mi = 0; mi < 4; ++mi)
    #pragma unroll
    for (int nf = 0; nf < 4; ++nf) {
      const int rr = mi * 16 + lhi * 4;
      const int cc = wc * 64 + nf * 16 + l15;
      #pragma unroll
      for (int i = 0; i < 4; ++i)
        yb[(size_t)(rr + i) * DM + cc] = acc[mi][nf][i];
    }
}

extern "C" void kernel_launch(void* const* d_in, const int* in_sizes, int n_in,
                              void* d_out, int out_size, void* d_ws, size_t ws_size,
                              hipStream_t stream) {
  const float* u      = (const float*)d_in[0];
  const float* Lam    = (const float*)d_in[1];
  const float* Bv     = (const float*)d_in[2];
  const float* Q      = (const float*)d_in[3];
  const float* log_dt = (const float*)d_in[4];
  float* out = (float*)d_out;

  const size_t nS  = (size_t)NCHUNK * BATCH * NST;           // 1 MB f32
  float* S  = (float*)d_ws;
  float* Xc = S + nS;                                        // 1 MB f32
  short* Qt = (short*)(Xc + nS);                             // 512 KB bf16
  short* XL = Qt + (size_t)DM * NST;                         // 32 MB bf16
  const size_t need = nS * 4 * 2 + (size_t)DM * NST * 2
                    + (size_t)BATCH * SEQ * NST * 2;         // 36,175,872 B

  if (ws_size >= need) {
    hipLaunchKernelGGL(k_transQ, dim3(64), dim3(256), 0, stream, Q, Qt);
    hipLaunchKernelGGL(k_scan_store, dim3(NCHUNK * BATCH), dim3(128), 0, stream,
                       u, Lam, Bv, log_dt, S, XL);
    hipLaunchKernelGGL(k_propagate, dim3(BATCH * NST / 256), dim3(256), 0, stream,
                       Lam, log_dt, S, Xc);
    hipLaunchKernelGGL(k_fusedB, dim3(NCHUNK * BATCH), dim3(512), 0, stream,
                       Lam, Bv, log_dt, Xc, XL, Qt, out);
  } else {
    // fallback: proven round-10 path
    hipLaunchKernelGGL(k_transQ, dim3(64), dim3(256), 0, stream, Q, Qt);
    hipLaunchKernelGGL(k_scan_sums, dim3(NCHUNK * BATCH), dim3(128), 0, stream,
                       u, Lam, Bv, log_dt, S);
    hipLaunchKernelGGL(k_propagate, dim3(BATCH * NST / 256), dim3(256), 0, stream,
                       Lam, log_dt, S, Xc);
    hipLaunchKernelGGL(k_fused, dim3(NCHUNK * BATCH), dim3(512), 0, stream,
                       u, Lam, Bv, log_dt, Xc, Qt, out);
  }
}